// Round 9
// baseline (130.242 us; speedup 1.0000x reference)
//
#include <hip/hip_runtime.h>
#include <math.h>

typedef float  f32x4   __attribute__((ext_vector_type(4)));
typedef __bf16 bf16x8  __attribute__((ext_vector_type(8)));
typedef __bf16 bf16x16 __attribute__((ext_vector_type(16)));

#define HP_     160
#define PITCH_  (HP_*64)           // elems per padded row
#define BPITCH_ (HP_*HP_*64)       // elems per batch

// swizzled row: 128B rows, XOR byte-bits 4..6 with row&7 (T2/G4)
#define SWZ(row, cb) ((row)*128 + ((cb) ^ (((row)&7)<<4)))

// channel permutation n(c): lane lg's 16 needed channels (orig {lg*8..+7,
// 32+lg*8..+7}) are the contiguous 32B chunk at element offset lg*16.

// ws layout (bytes):
//   xp  : [8][160][160][64] bf16 = 26214400  (zero halo, permuted channels)
//   wtb : [9][64][64] bf16 pre-swizzled+permuted = 73728
//   owt : [9][32][64] bf16 LINEAR+permuted = 36864 (rows 18..31 zero)
#define XP_BYTES   26214400
#define WTB_BYTES  73728

__device__ __forceinline__ void gl_lds16(const void* g, void* l) {
    __builtin_amdgcn_global_load_lds(
        (const __attribute__((address_space(1))) void*)g,
        (__attribute__((address_space(3))) void*)l, 16, 0, 0);
}

__device__ __forceinline__ float clip8(float v) {
    return fminf(8.f, fmaxf(-8.f, v));
}

// ---------------------------------------------------------------------------
// k_prep: [0,2048) NCHW f32 -> padded NHWC bf16, channels permuted;
//         [2048,4352) halo zero; [4352,4496) weights (wtb swizzled, owt linear)
// ---------------------------------------------------------------------------
__global__ __launch_bounds__(256) void k_prep(const float* __restrict__ x,
                                              const float* __restrict__ w,
                                              const float* __restrict__ ow,
                                              __bf16* __restrict__ xp,
                                              __bf16* __restrict__ wtb,
                                              __bf16* __restrict__ owt) {
    int gid = blockIdx.x, tid = threadIdx.x;
    if (gid < 2048) {
        __shared__ float tile[64][65];
        int b = gid & 7, rem = gid >> 3;
        int w0 = (rem & 1) * 64, h = (rem >> 1) & 127;
        int lw = tid & 63, cq4 = tid >> 6;
        const float* xb = x + ((size_t)b * 64) * 16384 + (size_t)h * 128;
        #pragma unroll
        for (int it = 0; it < 16; ++it) {
            int c = it * 4 + cq4;
            tile[c][lw] = xb[(size_t)c * 16384 + w0 + lw];
        }
        __syncthreads();
        int p = tid >> 2, q = tid & 3;
        bf16x8 v0, v1;
        #pragma unroll
        for (int j = 0; j < 8; ++j) {
            v0[j] = (__bf16)tile[q * 8 + j][p];
            v1[j] = (__bf16)tile[32 + q * 8 + j][p];
        }
        __bf16* dst = xp + (size_t)b * BPITCH_ + (size_t)(h + 16) * PITCH_
                         + (size_t)(w0 + p + 16) * 64 + q * 16;
        *(bf16x8*)dst = v0;
        *(bf16x8*)(dst + 8) = v1;
    } else if (gid < 4352) {
        int i = (gid - 2048) * 256 + tid;
        int b, y, xc, cc;
        if (i < 327680) {
            b = i / 40960; int r = i % 40960;
            int row = r / 1280; y = row < 16 ? row : row + 128;
            int xi = r % 1280; xc = xi >> 3; cc = (xi & 7) * 8;
        } else {
            int j = i - 327680;
            b = j / 32768; int r = j % 32768;
            y = 16 + (r >> 8);
            int xi = r & 255; int xcol = xi >> 3;
            xc = xcol < 16 ? xcol : xcol + 128; cc = (xi & 7) * 8;
        }
        bf16x8 z;
        #pragma unroll
        for (int j = 0; j < 8; ++j) z[j] = (__bf16)0.f;
        *(bf16x8*)(xp + (size_t)b * BPITCH_ + (size_t)y * PITCH_ + (size_t)xc * 64 + cc) = z;
    } else {
        int i = (gid - 4352) * 256 + tid;
        if (i < 36864) {   // wtb: pre-swizzled (consumed via SWZ'd ds_read)
            int c = i & 63, o = (i >> 6) & 63, k = i >> 12;
            int n = ((c >> 3) & 3) * 16 + ((c >> 5) << 3) + (c & 7);
            wtb[(k << 12) + (o << 6) + (n ^ ((o & 7) << 3))] = (__bf16)w[(o * 64 + c) * 9 + k];
        }
        if (i < 18432) {   // owt: LINEAR (consumed directly from global)
            int c = i & 63, o = (i >> 6) & 31, k = i >> 11;
            int n = ((c >> 3) & 3) * 16 + ((c >> 5) << 3) + (c & 7);
            owt[(k << 11) + (o << 6) + n] =
                (o < 18) ? (__bf16)ow[(o * 64 + c) * 9 + k] : (__bf16)0.f;
        }
    }
}

// ---------------------------------------------------------------------------
// k_main: fused offset-conv + deformable conv, TLP-first structure.
//   LDS = 2x8KB weight double-buffer + offl = 21KB -> 4 blocks/CU with
//   __launch_bounds__(256,4): 16 waves/CU (50%), 4 waves/SIMD. Gather latency
//   is hidden by OTHER WAVES, not register prefetch (r4-r8 lesson: compiler
//   never keeps prefetch banks live).
//   Phase 1 (offconv): A-frags straight from global owt, B from padded xp,
//     MFMA, clip -> offl. Tap-0 deform weights DMA'd under it.
//   Phase 2 per tap: {offl read -> 8 indep 16B gathers -> stage next tap's
//     weights (gl_lds) -> interp -> 8 ds_read A + 8 MFMA -> syncthreads}.
//   One barrier per tap; barrier drain doubles as DMA completion.
// ---------------------------------------------------------------------------
struct Bank { bf16x16 c00, c01, c10, c11; float ty, tx; };

__device__ __forceinline__ void load_bank(float2 od, int k, Bank& bk,
                                          float fh, float fw,
                                          const __bf16* xb) {
    float sy = od.x + (float)(k / 3) + fh;
    float sx = od.y + (float)(k % 3) + fw;
    float yf = floorf(sy), xf = floorf(sx);
    bk.ty = sy - yf; bk.tx = sx - xf;
    int yi = (int)yf, xi = (int)xf;
    const __bf16* s0 = xb + (yi * HP_ + xi) * 64;
    bk.c00 = *(const bf16x16*)(s0);
    bk.c01 = *(const bf16x16*)(s0 + 64);
    bk.c10 = *(const bf16x16*)(s0 + PITCH_);
    bk.c11 = *(const bf16x16*)(s0 + PITCH_ + 64);
}

__device__ __forceinline__ void interp(const Bank& bk, bf16x8& b0, bf16x8& b1) {
    float ty = bk.ty, tx = bk.tx;
    float w00 = (1.f - ty) * (1.f - tx), w01 = (1.f - ty) * tx;
    float w10 = ty * (1.f - tx),         w11 = ty * tx;
    #pragma unroll
    for (int j = 0; j < 8; ++j) {
        b0[j] = (__bf16)(w00 * (float)bk.c00[j] + w01 * (float)bk.c01[j]
                       + w10 * (float)bk.c10[j] + w11 * (float)bk.c11[j]);
        b1[j] = (__bf16)(w00 * (float)bk.c00[8 + j] + w01 * (float)bk.c01[8 + j]
                       + w10 * (float)bk.c10[8 + j] + w11 * (float)bk.c11[8 + j]);
    }
}

__global__ __launch_bounds__(256, 4) void k_main(const __bf16* __restrict__ xp,
                                                 const __bf16* __restrict__ wtb,
                                                 const __bf16* __restrict__ owt,
                                                 const float* __restrict__ off_b,
                                                 float* __restrict__ out) {
    __shared__ alignas(16) char wl[2][8192];    // weight double-buffer
    __shared__ float offl[64][18];              // clipped offsets

    int gid = blockIdx.x, tid = threadIdx.x;
    int b = gid & 7, rem = gid >> 3;            // XCD i <- batch i (L2 local)
    int w0 = (rem & 1) * 64, h = (rem >> 1) & 127;
    int lane = tid & 63, wv = tid >> 6, l15 = lane & 15, lg = lane >> 4;
    int px = wv * 16 + l15;

    // stage tap-0 deform weights into wl[0] (drained by phase-1 barrier)
    {
        const char* s = (const char*)wtb + wv * 2048 + lane * 16;
        char* d = (char*)wl[0] + wv * 2048;
        gl_lds16(s, d);
        gl_lds16(s + 1024, d + 1024);
    }

    // ---- phase 1: offset conv (A-frags straight from global owt) ----
    f32x4 acc0, acc1;
    #pragma unroll
    for (int r = 0; r < 4; ++r) {
        int o = lg * 4 + r;
        acc0[r] = (o < 18) ? off_b[o] : 0.f;
        acc1[r] = (o + 16 < 18) ? off_b[o + 16] : 0.f;
    }

    const __bf16* pbase = xp + (size_t)b * BPITCH_ + (size_t)(h + 15) * PITCH_
                             + (size_t)(w0 + px + 15) * 64 + lg * 16;
    #pragma unroll
    for (int t = 0; t < 9; ++t) {
        bf16x16 bv = *(const bf16x16*)(pbase + (t / 3) * PITCH_ + (t % 3) * 64);
        bf16x8 b0 = __builtin_shufflevector(bv, bv, 0, 1, 2, 3, 4, 5, 6, 7);
        bf16x8 b1 = __builtin_shufflevector(bv, bv, 8, 9, 10, 11, 12, 13, 14, 15);
        const __bf16* ao = owt + t * 2048 + l15 * 64 + lg * 16;
        bf16x8 a00 = *(const bf16x8*)(ao);
        bf16x8 a01 = *(const bf16x8*)(ao + 8);
        bf16x8 a10 = *(const bf16x8*)(ao + 1024);
        bf16x8 a11 = *(const bf16x8*)(ao + 1032);
        acc0 = __builtin_amdgcn_mfma_f32_16x16x32_bf16(a00, b0, acc0, 0, 0, 0);
        acc0 = __builtin_amdgcn_mfma_f32_16x16x32_bf16(a01, b1, acc0, 0, 0, 0);
        acc1 = __builtin_amdgcn_mfma_f32_16x16x32_bf16(a10, b0, acc1, 0, 0, 0);
        acc1 = __builtin_amdgcn_mfma_f32_16x16x32_bf16(a11, b1, acc1, 0, 0, 0);
    }
    #pragma unroll
    for (int r = 0; r < 4; ++r) offl[px][lg * 4 + r] = clip8(acc0[r]);
    if (lg == 0) { offl[px][16] = clip8(acc1[0]); offl[px][17] = clip8(acc1[1]); }
    __syncthreads();     // offl ready AND tap-0 weight DMA drained

    // ---- phase 2: per-tap {gather -> stage next -> interp -> MFMA -> bar} --
    const __bf16* xb = xp + (size_t)b * BPITCH_ + lg * 16;
    float fh = (float)(h + 15);        // h-1+16 (pad)
    float fw = (float)(w0 + px + 15);  // w-1+16 (pad)

    f32x4 acc[4];
    #pragma unroll
    for (int mi = 0; mi < 4; ++mi)
        #pragma unroll
        for (int r = 0; r < 4; ++r) acc[mi][r] = 0.f;

    #pragma unroll
    for (int t = 0; t < 9; ++t) {
        float2 od = *(const float2*)&offl[px][2 * t];
        Bank bk;
        load_bank(od, t, bk, fh, fw, xb);       // 8 independent 16B gathers

        if (t < 8) {                            // stage tap t+1 -> other buf
            const char* s = (const char*)wtb + (t + 1) * 8192 + wv * 2048 + lane * 16;
            char* d = (char*)wl[(t + 1) & 1] + wv * 2048;
            gl_lds16(s, d);
            gl_lds16(s + 1024, d + 1024);
        }

        bf16x8 b0, b1;
        interp(bk, b0, b1);                     // waits on own gathers only

        const char* wb = (const char*)wl[t & 1];
        #pragma unroll
        for (int mi = 0; mi < 4; ++mi) {
            bf16x8 a0 = *(const bf16x8*)(wb + SWZ(mi * 16 + l15, lg * 32));
            bf16x8 a1 = *(const bf16x8*)(wb + SWZ(mi * 16 + l15, lg * 32 + 16));
            acc[mi] = __builtin_amdgcn_mfma_f32_16x16x32_bf16(a0, b0, acc[mi], 0, 0, 0);
            acc[mi] = __builtin_amdgcn_mfma_f32_16x16x32_bf16(a1, b1, acc[mi], 0, 0, 0);
        }
        __syncthreads();                        // wl swap safe + DMA drained
    }

    // epilogue: out[b][o][h][w];  o = mi*16 + lg*4 + r, px = col
    #pragma unroll
    for (int mi = 0; mi < 4; ++mi) {
        float* ob = out + ((size_t)b * 64 + mi * 16 + lg * 4) * 16384
                        + (size_t)h * 128 + w0 + px;
        ob[0]     = acc[mi][0];
        ob[16384] = acc[mi][1];
        ob[32768] = acc[mi][2];
        ob[49152] = acc[mi][3];
    }
}

// ---------------------------------------------------------------------------
extern "C" void kernel_launch(void* const* d_in, const int* in_sizes, int n_in,
                              void* d_out, int out_size, void* d_ws, size_t ws_size,
                              hipStream_t stream) {
    const float* x      = (const float*)d_in[0];
    const float* weight = (const float*)d_in[1];
    const float* off_w  = (const float*)d_in[2];
    const float* off_b  = (const float*)d_in[3];
    float* out = (float*)d_out;

    char* ws = (char*)d_ws;
    __bf16* xp  = (__bf16*)ws;
    __bf16* wtb = (__bf16*)(ws + XP_BYTES);
    __bf16* owt = (__bf16*)(ws + XP_BYTES + WTB_BYTES);

    k_prep<<<4496, 256, 0, stream>>>(x, weight, off_w, xp, wtb, owt);
    k_main<<<2048, 256, 0, stream>>>(xp, wtb, owt, off_b, out);
}

// Round 10
// 127.892 us; speedup vs baseline: 1.0184x; 1.0184x over previous
//
#include <hip/hip_runtime.h>
#include <math.h>

typedef float  f32x4   __attribute__((ext_vector_type(4)));
typedef __bf16 bf16x8  __attribute__((ext_vector_type(8)));
typedef __bf16 bf16x16 __attribute__((ext_vector_type(16)));

#define HP_     160
#define PITCH_  (HP_*64)           // elems per padded row
#define BPITCH_ (HP_*HP_*64)       // elems per batch

// swizzled row: 128B rows, XOR byte-bits 4..6 with row&7 (T2/G4)
#define SWZ(row, cb) ((row)*128 + ((cb) ^ (((row)&7)<<4)))

// channel permutation n(c): lane lg's 16 needed channels (orig {lg*8..+7,
// 32+lg*8..+7}) are the contiguous 32B chunk at element offset lg*16.

// ws layout (bytes):
//   xp  : [8][160][160][64] bf16 = 26214400  (zero halo, permuted channels)
//   wtb : [9][64][64] bf16 pre-swizzled+permuted = 73728
//   owt : [9][32][64] bf16 LINEAR+permuted = 36864 (rows 18..31 zero)
#define XP_BYTES   26214400
#define WTB_BYTES  73728

__device__ __forceinline__ void gl_lds16(const void* g, void* l) {
    __builtin_amdgcn_global_load_lds(
        (const __attribute__((address_space(1))) void*)g,
        (__attribute__((address_space(3))) void*)l, 16, 0, 0);
}

__device__ __forceinline__ float clip8(float v) {
    return fminf(8.f, fmaxf(-8.f, v));
}

// ---------------------------------------------------------------------------
// k_prep: identical to r9 (verified): padded NHWC bf16 + halo zero + weights
// ---------------------------------------------------------------------------
__global__ __launch_bounds__(256) void k_prep(const float* __restrict__ x,
                                              const float* __restrict__ w,
                                              const float* __restrict__ ow,
                                              __bf16* __restrict__ xp,
                                              __bf16* __restrict__ wtb,
                                              __bf16* __restrict__ owt) {
    int gid = blockIdx.x, tid = threadIdx.x;
    if (gid < 2048) {
        __shared__ float tile[64][65];
        int b = gid & 7, rem = gid >> 3;
        int w0 = (rem & 1) * 64, h = (rem >> 1) & 127;
        int lw = tid & 63, cq4 = tid >> 6;
        const float* xb = x + ((size_t)b * 64) * 16384 + (size_t)h * 128;
        #pragma unroll
        for (int it = 0; it < 16; ++it) {
            int c = it * 4 + cq4;
            tile[c][lw] = xb[(size_t)c * 16384 + w0 + lw];
        }
        __syncthreads();
        int p = tid >> 2, q = tid & 3;
        bf16x8 v0, v1;
        #pragma unroll
        for (int j = 0; j < 8; ++j) {
            v0[j] = (__bf16)tile[q * 8 + j][p];
            v1[j] = (__bf16)tile[32 + q * 8 + j][p];
        }
        __bf16* dst = xp + (size_t)b * BPITCH_ + (size_t)(h + 16) * PITCH_
                         + (size_t)(w0 + p + 16) * 64 + q * 16;
        *(bf16x8*)dst = v0;
        *(bf16x8*)(dst + 8) = v1;
    } else if (gid < 4352) {
        int i = (gid - 2048) * 256 + tid;
        int b, y, xc, cc;
        if (i < 327680) {
            b = i / 40960; int r = i % 40960;
            int row = r / 1280; y = row < 16 ? row : row + 128;
            int xi = r % 1280; xc = xi >> 3; cc = (xi & 7) * 8;
        } else {
            int j = i - 327680;
            b = j / 32768; int r = j % 32768;
            y = 16 + (r >> 8);
            int xi = r & 255; int xcol = xi >> 3;
            xc = xcol < 16 ? xcol : xcol + 128; cc = (xi & 7) * 8;
        }
        bf16x8 z;
        #pragma unroll
        for (int j = 0; j < 8; ++j) z[j] = (__bf16)0.f;
        *(bf16x8*)(xp + (size_t)b * BPITCH_ + (size_t)y * PITCH_ + (size_t)xc * 64 + cc) = z;
    } else {
        int i = (gid - 4352) * 256 + tid;
        if (i < 36864) {   // wtb: pre-swizzled (consumed via SWZ'd ds_read)
            int c = i & 63, o = (i >> 6) & 63, k = i >> 12;
            int n = ((c >> 3) & 3) * 16 + ((c >> 5) << 3) + (c & 7);
            wtb[(k << 12) + (o << 6) + (n ^ ((o & 7) << 3))] = (__bf16)w[(o * 64 + c) * 9 + k];
        }
        if (i < 18432) {   // owt: LINEAR (consumed directly from global)
            int c = i & 63, o = (i >> 6) & 31, k = i >> 11;
            int n = ((c >> 3) & 3) * 16 + ((c >> 5) << 3) + (c & 7);
            owt[(k << 11) + (o << 6) + n] =
                (o < 18) ? (__bf16)ow[(o * 64 + c) * 9 + k] : (__bf16)0.f;
        }
    }
}

// ---------------------------------------------------------------------------
// k_main: fused offset-conv + deformable conv, asm-pipelined gathers.
//   All 9 deform weight taps -> 72KB LDS (DMA under phase 1; the single
//   __syncthreads drains it, so phase-2 vmcnt counts ONLY our asm gathers).
//   Phase 2, per tap t: dataflow-tied s_waitcnt vmcnt(8) on bank[t&1] ->
//   interp -> asm-issue bank t+2 into freed regs -> 8 LDS A-frags + 8 MFMA.
//   Tap 8 waits vmcnt(0). No in-loop barriers; loads provably span a full
//   tap of work (AITER pattern: counted vmcnt, never 0 until the end).
// ---------------------------------------------------------------------------
struct BankR { bf16x8 c[8]; float ty, tx; };

// issue 8 independent 16B gathers for one tap; volatile asm cannot be sunk
__device__ __forceinline__ void issue_bank(float2 od, int k, BankR& bk,
                                           float fh, float fw,
                                           const __bf16* xb) {
    float sy = od.x + (float)(k / 3) + fh;
    float sx = od.y + (float)(k % 3) + fw;
    float yf = floorf(sy), xf = floorf(sx);
    bk.ty = sy - yf; bk.tx = sx - xf;
    int yi = (int)yf, xi = (int)xf;
    const __bf16* s0 = xb + (yi * HP_ + xi) * 64;   // (y0,x0) 32B chunk
    const __bf16* s1 = s0 + PITCH_;                 // (y1,x0)
    asm volatile(
        "global_load_dwordx4 %0, %8, off\n\t"
        "global_load_dwordx4 %1, %8, off offset:16\n\t"
        "global_load_dwordx4 %2, %8, off offset:128\n\t"
        "global_load_dwordx4 %3, %8, off offset:144\n\t"
        "global_load_dwordx4 %4, %9, off\n\t"
        "global_load_dwordx4 %5, %9, off offset:16\n\t"
        "global_load_dwordx4 %6, %9, off offset:128\n\t"
        "global_load_dwordx4 %7, %9, off offset:144\n\t"
        : "=&v"(bk.c[0]), "=&v"(bk.c[1]), "=&v"(bk.c[2]), "=&v"(bk.c[3]),
          "=&v"(bk.c[4]), "=&v"(bk.c[5]), "=&v"(bk.c[6]), "=&v"(bk.c[7])
        : "v"(s0), "v"(s1));
}

// dataflow-tied waits: consumers of bk.c are ordered AFTER the waitcnt
__device__ __forceinline__ void wait_bank8(BankR& bk) {
    asm volatile("s_waitcnt vmcnt(8)"
        : "+v"(bk.c[0]), "+v"(bk.c[1]), "+v"(bk.c[2]), "+v"(bk.c[3]),
          "+v"(bk.c[4]), "+v"(bk.c[5]), "+v"(bk.c[6]), "+v"(bk.c[7]));
}
__device__ __forceinline__ void wait_bank0(BankR& bk) {
    asm volatile("s_waitcnt vmcnt(0)"
        : "+v"(bk.c[0]), "+v"(bk.c[1]), "+v"(bk.c[2]), "+v"(bk.c[3]),
          "+v"(bk.c[4]), "+v"(bk.c[5]), "+v"(bk.c[6]), "+v"(bk.c[7]));
}

__device__ __forceinline__ void interp(const BankR& bk, bf16x8& b0, bf16x8& b1) {
    float ty = bk.ty, tx = bk.tx;
    float w00 = (1.f - ty) * (1.f - tx), w01 = (1.f - ty) * tx;
    float w10 = ty * (1.f - tx),         w11 = ty * tx;
    #pragma unroll
    for (int j = 0; j < 8; ++j) {
        b0[j] = (__bf16)(w00 * (float)bk.c[0][j] + w01 * (float)bk.c[2][j]
                       + w10 * (float)bk.c[4][j] + w11 * (float)bk.c[6][j]);
        b1[j] = (__bf16)(w00 * (float)bk.c[1][j] + w01 * (float)bk.c[3][j]
                       + w10 * (float)bk.c[5][j] + w11 * (float)bk.c[7][j]);
    }
}

__global__ __launch_bounds__(256, 2) void k_main(const __bf16* __restrict__ xp,
                                                 const __bf16* __restrict__ wtb,
                                                 const __bf16* __restrict__ owt,
                                                 const float* __restrict__ off_b,
                                                 float* __restrict__ out) {
    __shared__ alignas(16) char wl[73728];      // all 9 taps, swizzled rows
    __shared__ float offl[64][20];              // clipped offsets (padded row)

    int gid = blockIdx.x, tid = threadIdx.x;
    int b = gid & 7, rem = gid >> 3;            // XCD i <- batch i (L2 local)
    int w0 = (rem & 1) * 64, h = (rem >> 1) & 127;
    int lane = tid & 63, wv = tid >> 6, l15 = lane & 15, lg = lane >> 4;
    int px = wv * 16 + l15;

    {   // DMA all 9 deform weight taps -> LDS (completes under phase 1)
        const char* s = (const char*)wtb + wv * 18432 + lane * 16;
        char* d = wl + wv * 18432;
        #pragma unroll
        for (int i = 0; i < 18; ++i) gl_lds16(s + i * 1024, d + i * 1024);
    }

    // ---- phase 1: offset conv (A-frags straight from global owt) ----
    f32x4 acc0, acc1;
    #pragma unroll
    for (int r = 0; r < 4; ++r) {
        int o = lg * 4 + r;
        acc0[r] = (o < 18) ? off_b[o] : 0.f;
        acc1[r] = (o + 16 < 18) ? off_b[o + 16] : 0.f;
    }

    const __bf16* pbase = xp + (size_t)b * BPITCH_ + (size_t)(h + 15) * PITCH_
                             + (size_t)(w0 + px + 15) * 64 + lg * 16;
    #pragma unroll
    for (int t = 0; t < 9; ++t) {
        bf16x16 bv = *(const bf16x16*)(pbase + (t / 3) * PITCH_ + (t % 3) * 64);
        bf16x8 b0 = __builtin_shufflevector(bv, bv, 0, 1, 2, 3, 4, 5, 6, 7);
        bf16x8 b1 = __builtin_shufflevector(bv, bv, 8, 9, 10, 11, 12, 13, 14, 15);
        const __bf16* ao = owt + t * 2048 + l15 * 64 + lg * 16;
        bf16x8 a00 = *(const bf16x8*)(ao);
        bf16x8 a01 = *(const bf16x8*)(ao + 8);
        bf16x8 a10 = *(const bf16x8*)(ao + 1024);
        bf16x8 a11 = *(const bf16x8*)(ao + 1032);
        acc0 = __builtin_amdgcn_mfma_f32_16x16x32_bf16(a00, b0, acc0, 0, 0, 0);
        acc0 = __builtin_amdgcn_mfma_f32_16x16x32_bf16(a01, b1, acc0, 0, 0, 0);
        acc1 = __builtin_amdgcn_mfma_f32_16x16x32_bf16(a10, b0, acc1, 0, 0, 0);
        acc1 = __builtin_amdgcn_mfma_f32_16x16x32_bf16(a11, b1, acc1, 0, 0, 0);
    }
    #pragma unroll
    for (int r = 0; r < 4; ++r) offl[px][lg * 4 + r] = clip8(acc0[r]);
    if (lg == 0) { offl[px][16] = clip8(acc1[0]); offl[px][17] = clip8(acc1[1]); }
    __syncthreads();     // offl ready AND weight DMA + all phase-1 vmem drained

    // ---- phase 2: asm-pipelined gathers, counted vmcnt, no barriers ----
    const __bf16* xb = xp + (size_t)b * BPITCH_ + lg * 16;
    float fh = (float)(h + 15);        // h-1+16 (pad)
    float fw = (float)(w0 + px + 15);  // w-1+16 (pad)

    f32x4 acc[4];
    #pragma unroll
    for (int mi = 0; mi < 4; ++mi)
        #pragma unroll
        for (int r = 0; r < 4; ++r) acc[mi][r] = 0.f;

    BankR bank0, bank1;
    {
        float2 od0 = *(const float2*)&offl[px][0];
        float2 od1 = *(const float2*)&offl[px][2];
        issue_bank(od0, 0, bank0, fh, fw, xb);
        issue_bank(od1, 1, bank1, fh, fw, xb);
    }

    #pragma unroll
    for (int t = 0; t < 9; ++t) {
        BankR& cur = (t & 1) ? bank1 : bank0;
        if (t < 8) wait_bank8(cur); else wait_bank0(cur);

        bf16x8 b0, b1;
        interp(cur, b0, b1);

        if (t < 7) {   // reuse freed regs; volatile issue can't sink
            float2 odn = *(const float2*)&offl[px][2 * (t + 2)];
            issue_bank(odn, t + 2, cur, fh, fw, xb);
        }

        const char* wb = wl + t * 8192;
        #pragma unroll
        for (int mi = 0; mi < 4; ++mi) {
            bf16x8 a0 = *(const bf16x8*)(wb + SWZ(mi * 16 + l15, lg * 32));
            bf16x8 a1 = *(const bf16x8*)(wb + SWZ(mi * 16 + l15, lg * 32 + 16));
            acc[mi] = __builtin_amdgcn_mfma_f32_16x16x32_bf16(a0, b0, acc[mi], 0, 0, 0);
            acc[mi] = __builtin_amdgcn_mfma_f32_16x16x32_bf16(a1, b1, acc[mi], 0, 0, 0);
        }
    }

    // epilogue: out[b][o][h][w];  o = mi*16 + lg*4 + r, px = col
    #pragma unroll
    for (int mi = 0; mi < 4; ++mi) {
        float* ob = out + ((size_t)b * 64 + mi * 16 + lg * 4) * 16384
                        + (size_t)h * 128 + w0 + px;
        ob[0]     = acc[mi][0];
        ob[16384] = acc[mi][1];
        ob[32768] = acc[mi][2];
        ob[49152] = acc[mi][3];
    }
}

// ---------------------------------------------------------------------------
extern "C" void kernel_launch(void* const* d_in, const int* in_sizes, int n_in,
                              void* d_out, int out_size, void* d_ws, size_t ws_size,
                              hipStream_t stream) {
    const float* x      = (const float*)d_in[0];
    const float* weight = (const float*)d_in[1];
    const float* off_w  = (const float*)d_in[2];
    const float* off_b  = (const float*)d_in[3];
    float* out = (float*)d_out;

    char* ws = (char*)d_ws;
    __bf16* xp  = (__bf16*)ws;
    __bf16* wtb = (__bf16*)(ws + XP_BYTES);
    __bf16* owt = (__bf16*)(ws + XP_BYTES + WTB_BYTES);

    k_prep<<<4496, 256, 0, stream>>>(x, weight, off_w, xp, wtb, owt);
    k_main<<<2048, 256, 0, stream>>>(xp, wtb, owt, off_b, out);
}